// Round 1
// baseline (101.765 us; speedup 1.0000x reference)
//
#include <hip/hip_runtime.h>

#define N  35
#define E  (N*N)
#define C1 256
#define C2 256
#define C3 128

// Workspace layout (floats):
//   h1   @ 0      : 35*256 = 8960
//   h2   @ 8960   : 35*256 = 8960
//   h3   @ 17920  : 35*128 = 4480
//   agg2 @ 22400  : 35*256 = 8960   (atomic accumulators, zeroed each call)
//   agg3 @ 31360  : 35*128 = 4480
// total 35840 floats = 143,360 bytes

// ---------------- Layer 1: cin=1, cout=256 ----------------
__global__ __launch_bounds__(C1) void k_layer1(
    const float* __restrict__ x, const float* __restrict__ ea,
    const float* __restrict__ nn1w, const float* __restrict__ nn1b,
    const float* __restrict__ root1, const float* __restrict__ bias1,
    float* __restrict__ h1)
{
    int j = blockIdx.x;
    int o = threadIdx.x;
    float w[6];
#pragma unroll
    for (int v = 0; v < 6; ++v) w[v] = nn1w[v * C1 + o];
    float b = nn1b[o];
    float acc = 0.f;
    for (int i = 0; i < N; ++i) {
        int e = i * N + j;                 // src=i, dst=j
        float p = b;
#pragma unroll
        for (int v = 0; v < 6; ++v) p = fmaf(ea[e * 6 + v], w[v], p);
        p = fmaxf(p, 0.f);
        acc = fmaf(x[i], p, acc);
    }
    float s = acc * (1.f / N) + x[j] * root1[o] + bias1[o];
    h1[j * C1 + o] = fmaxf(s, 0.f);
}

// ---------------- Layer 2 msg: cin=256, cout=256 ----------------
#define CSPL2 16
#define CL2   (C1 / CSPL2)   // 16 c's per block
__global__ __launch_bounds__(256) void k_l2msg(
    const float* __restrict__ ea,
    const float* __restrict__ w2, const float* __restrict__ b2,
    const float* __restrict__ h1, float* __restrict__ agg2)
{
    int j     = blockIdx.x % N;
    int chunk = blockIdx.x / N;
    int c0    = chunk * CL2;
    int o     = threadIdx.x;

    __shared__ float ea_s[N * 6];
    __shared__ float h1_s[N * CL2];
    if (o < N * 6) {
        int i = o / 6, v = o % 6;
        ea_s[o] = ea[(i * N + j) * 6 + v];
    }
    for (int t = o; t < N * CL2; t += 256) {
        int i = t / CL2, cc = t % CL2;
        h1_s[t] = h1[i * C1 + c0 + cc];
    }
    __syncthreads();

    float acc = 0.f;
    for (int cc = 0; cc < CL2; ++cc) {
        int col = (c0 + cc) * C2 + o;
        float w0 = w2[0 * C1 * C2 + col];
        float w1 = w2[1 * C1 * C2 + col];
        float w2v = w2[2 * C1 * C2 + col];
        float w3v = w2[3 * C1 * C2 + col];
        float w4 = w2[4 * C1 * C2 + col];
        float w5 = w2[5 * C1 * C2 + col];
        float b  = b2[col];
#pragma unroll 7
        for (int i = 0; i < N; ++i) {
            float p = fmaf(ea_s[i * 6 + 0], w0, b);
            p = fmaf(ea_s[i * 6 + 1], w1, p);
            p = fmaf(ea_s[i * 6 + 2], w2v, p);
            p = fmaf(ea_s[i * 6 + 3], w3v, p);
            p = fmaf(ea_s[i * 6 + 4], w4, p);
            p = fmaf(ea_s[i * 6 + 5], w5, p);
            p = fmaxf(p, 0.f);
            acc = fmaf(h1_s[i * CL2 + cc], p, acc);
        }
    }
    atomicAdd(&agg2[j * C2 + o], acc);
}

// ---------------- Layer 2 finalize ----------------
__global__ __launch_bounds__(C2) void k_l2fin(
    const float* __restrict__ agg2, const float* __restrict__ h1,
    const float* __restrict__ root2, const float* __restrict__ bias2,
    float* __restrict__ h2)
{
    int j = blockIdx.x, o = threadIdx.x;
    __shared__ float hrow[C1];
    hrow[o] = h1[j * C1 + o];
    __syncthreads();
    float s = agg2[j * C2 + o] * (1.f / N) + bias2[o];
    for (int c = 0; c < C1; ++c) s = fmaf(hrow[c], root2[c * C2 + o], s);
    h2[j * C2 + o] = fmaxf(s, 0.f);
}

// ---------------- Layer 3 msg: cin=256, cout=128 ----------------
#define CSPL3 16
#define CL3   (C2 / CSPL3)   // 16 c's per block; 2 halves of 8 per thread-group
__global__ __launch_bounds__(256) void k_l3msg(
    const float* __restrict__ ea,
    const float* __restrict__ w3, const float* __restrict__ b3,
    const float* __restrict__ h2, float* __restrict__ agg3)
{
    int j     = blockIdx.x % N;
    int chunk = blockIdx.x / N;
    int c0    = chunk * CL3;
    int tid   = threadIdx.x;
    int o     = tid & (C3 - 1);
    int half  = tid >> 7;

    __shared__ float ea_s[N * 6];
    __shared__ float h2_s[N * CL3];
    if (tid < N * 6) {
        int i = tid / 6, v = tid % 6;
        ea_s[tid] = ea[(i * N + j) * 6 + v];
    }
    for (int t = tid; t < N * CL3; t += 256) {
        int i = t / CL3, cc = t % CL3;
        h2_s[t] = h2[i * C2 + c0 + cc];
    }
    __syncthreads();

    float acc = 0.f;
    for (int cc2 = 0; cc2 < CL3 / 2; ++cc2) {
        int cc  = half * (CL3 / 2) + cc2;
        int col = (c0 + cc) * C3 + o;
        float w0 = w3[0 * C2 * C3 + col];
        float w1 = w3[1 * C2 * C3 + col];
        float w2v = w3[2 * C2 * C3 + col];
        float w3v = w3[3 * C2 * C3 + col];
        float w4 = w3[4 * C2 * C3 + col];
        float w5 = w3[5 * C2 * C3 + col];
        float b  = b3[col];
#pragma unroll 7
        for (int i = 0; i < N; ++i) {
            float p = fmaf(ea_s[i * 6 + 0], w0, b);
            p = fmaf(ea_s[i * 6 + 1], w1, p);
            p = fmaf(ea_s[i * 6 + 2], w2v, p);
            p = fmaf(ea_s[i * 6 + 3], w3v, p);
            p = fmaf(ea_s[i * 6 + 4], w4, p);
            p = fmaf(ea_s[i * 6 + 5], w5, p);
            p = fmaxf(p, 0.f);
            acc = fmaf(h2_s[i * CL3 + cc], p, acc);
        }
    }
    atomicAdd(&agg3[j * C3 + o], acc);
}

// ---------------- Layer 3 finalize ----------------
__global__ __launch_bounds__(C3) void k_l3fin(
    const float* __restrict__ agg3, const float* __restrict__ h2,
    const float* __restrict__ root3, const float* __restrict__ bias3,
    float* __restrict__ h3)
{
    int j = blockIdx.x, o = threadIdx.x;
    __shared__ float hrow[C2];
    for (int t = o; t < C2; t += C3) hrow[t] = h2[j * C2 + t];
    __syncthreads();
    float s = agg3[j * C3 + o] * (1.f / N) + bias3[o];
    for (int c = 0; c < C2; ++c) s = fmaf(hrow[c], root3[c * C3 + o], s);
    h3[j * C3 + o] = fmaxf(s, 0.f);
}

// ---------------- CBT: pairwise L1 distance ----------------
__global__ __launch_bounds__(256) void k_cbt(
    const float* __restrict__ h3, float* __restrict__ out)
{
    int t = blockIdx.x * 256 + threadIdx.x;
    if (t >= E) return;
    int i = t / N, j = t % N;
    const float4* hi = (const float4*)(h3 + i * C3);
    const float4* hj = (const float4*)(h3 + j * C3);
    float acc = 0.f;
#pragma unroll
    for (int f = 0; f < C3 / 4; ++f) {
        float4 a = hi[f], b = hj[f];
        acc += fabsf(b.x - a.x) + fabsf(b.y - a.y) + fabsf(b.z - a.z) + fabsf(b.w - a.w);
    }
    out[t] = acc;
}

extern "C" void kernel_launch(void* const* d_in, const int* in_sizes, int n_in,
                              void* d_out, int out_size, void* d_ws, size_t ws_size,
                              hipStream_t stream)
{
    const float* x     = (const float*)d_in[0];
    const float* ea    = (const float*)d_in[1];
    // d_in[2] = edge_index, unused: topology is static (src=e/35, dst=e%35)
    const float* nn1w  = (const float*)d_in[3];
    const float* nn1b  = (const float*)d_in[4];
    const float* nn2w  = (const float*)d_in[5];
    const float* nn2b  = (const float*)d_in[6];
    const float* nn3w  = (const float*)d_in[7];
    const float* nn3b  = (const float*)d_in[8];
    const float* root1 = (const float*)d_in[9];
    const float* bias1 = (const float*)d_in[10];
    const float* root2 = (const float*)d_in[11];
    const float* bias2 = (const float*)d_in[12];
    const float* root3 = (const float*)d_in[13];
    const float* bias3 = (const float*)d_in[14];

    float* ws   = (float*)d_ws;
    float* h1   = ws;
    float* h2   = ws + 8960;
    float* h3   = ws + 17920;
    float* agg2 = ws + 22400;
    float* agg3 = ws + 31360;

    // zero the atomic accumulators every call (d_ws is not re-poisoned)
    hipMemsetAsync(agg2, 0, (8960 + 4480) * sizeof(float), stream);

    k_layer1<<<N, C1, 0, stream>>>(x, ea, nn1w, nn1b, root1, bias1, h1);
    k_l2msg<<<N * CSPL2, 256, 0, stream>>>(ea, nn2w, nn2b, h1, agg2);
    k_l2fin<<<N, C2, 0, stream>>>(agg2, h1, root2, bias2, h2);
    k_l3msg<<<N * CSPL3, 256, 0, stream>>>(ea, nn3w, nn3b, h2, agg3);
    k_l3fin<<<N, C3, 0, stream>>>(agg3, h2, root3, bias3, h3);
    k_cbt<<<(E + 255) / 256, 256, 0, stream>>>(h3, (float*)d_out);
}

// Round 2
// 48.708 us; speedup vs baseline: 2.0893x; 2.0893x over previous
//
#include <hip/hip_runtime.h>

#define N  35
#define E  (N*N)
#define C1 256
#define C2 256
#define C3 128

// Workspace layout (floats):
//   h1   @ 0     : 35*256 = 8960
//   agg2 @ 8960  : 35*256 = 8960   (atomic accumulators, zeroed each call;
//   agg3 @ 17920 : 35*128 = 4480    hold PRE-activation: msg/35 + h@root. bias+relu at read.)

// ---------------- Layer 1: cin=1, cout=256 ----------------
__global__ __launch_bounds__(C1) void k_layer1(
    const float* __restrict__ x, const float* __restrict__ ea,
    const float* __restrict__ nn1w, const float* __restrict__ nn1b,
    const float* __restrict__ root1, const float* __restrict__ bias1,
    float* __restrict__ h1)
{
    int j = blockIdx.x;
    int o = threadIdx.x;
    float w[6];
#pragma unroll
    for (int v = 0; v < 6; ++v) w[v] = nn1w[v * C1 + o];
    float b = nn1b[o];
    float acc = 0.f;
    for (int i = 0; i < N; ++i) {
        int e = i * N + j;                 // src=i, dst=j
        float p = b;
#pragma unroll
        for (int v = 0; v < 6; ++v) p = fmaf(ea[e * 6 + v], w[v], p);
        p = fmaxf(p, 0.f);
        acc = fmaf(x[i], p, acc);
    }
    float s = acc * (1.f / N) + x[j] * root1[o] + bias1[o];
    h1[j * C1 + o] = fmaxf(s, 0.f);
}

// ---------------- Layer 2: msg chunks (32 x 8c) + root chunks (8 x 32c) ----------------
__global__ __launch_bounds__(256) void k_l2(
    const float* __restrict__ ea,
    const float* __restrict__ w2, const float* __restrict__ b2,
    const float* __restrict__ h1, const float* __restrict__ root2,
    float* __restrict__ agg2)
{
    const int j     = blockIdx.x % N;
    const int chunk = blockIdx.x / N;   // 0..39
    const int o     = threadIdx.x;

    if (chunk < 32) {
        const int c0 = chunk * 8;
        __shared__ float ea_s[N * 6];
        __shared__ float h1_s[N * 8];
        if (o < N * 6) { int i = o / 6, v = o % 6; ea_s[o] = ea[(i * N + j) * 6 + v]; }
        for (int t = o; t < N * 8; t += 256) {
            int i = t >> 3, cc = t & 7;
            h1_s[t] = h1[i * C1 + c0 + cc];
        }
        __syncthreads();

        float wv[8][6], bb[8], acc[8];
#pragma unroll
        for (int cc = 0; cc < 8; ++cc) {
            int col = (c0 + cc) * C2 + o;
#pragma unroll
            for (int v = 0; v < 6; ++v) wv[cc][v] = w2[v * (C1 * C2) + col];
            bb[cc] = b2[col];
            acc[cc] = 0.f;
        }
#pragma unroll 5
        for (int i = 0; i < N; ++i) {
            const float2 e01 = *(const float2*)&ea_s[i * 6];
            const float2 e23 = *(const float2*)&ea_s[i * 6 + 2];
            const float2 e45 = *(const float2*)&ea_s[i * 6 + 4];
            const float4 ha  = *(const float4*)&h1_s[i * 8];
            const float4 hb  = *(const float4*)&h1_s[i * 8 + 4];
            const float hv[8] = {ha.x, ha.y, ha.z, ha.w, hb.x, hb.y, hb.z, hb.w};
#pragma unroll
            for (int cc = 0; cc < 8; ++cc) {
                float p = fmaf(e01.x, wv[cc][0], bb[cc]);
                p = fmaf(e01.y, wv[cc][1], p);
                p = fmaf(e23.x, wv[cc][2], p);
                p = fmaf(e23.y, wv[cc][3], p);
                p = fmaf(e45.x, wv[cc][4], p);
                p = fmaf(e45.y, wv[cc][5], p);
                p = fmaxf(p, 0.f);
                acc[cc] = fmaf(hv[cc], p, acc[cc]);
            }
        }
        float s = 0.f;
#pragma unroll
        for (int cc = 0; cc < 8; ++cc) s += acc[cc];
        atomicAdd(&agg2[j * C2 + o], s * (1.f / N));
    } else {
        // root contribution: 32 c's per chunk
        const int c0 = (chunk - 32) * 32;
        float s = 0.f;
#pragma unroll 8
        for (int c = c0; c < c0 + 32; ++c)
            s = fmaf(h1[j * C1 + c], root2[c * C2 + o], s);
        atomicAdd(&agg2[j * C2 + o], s);
    }
}

// ---------------- Layer 3: msg chunks (32 x 8c) + root chunks (4 x 64c) ----------------
// h2(i,c) = relu(agg2[i,c] + bias2[c]) computed on the fly.
__global__ __launch_bounds__(256) void k_l3(
    const float* __restrict__ ea,
    const float* __restrict__ w3, const float* __restrict__ b3,
    const float* __restrict__ agg2, const float* __restrict__ bias2,
    const float* __restrict__ root3,
    float* __restrict__ agg3)
{
    const int j     = blockIdx.x % N;
    const int chunk = blockIdx.x / N;   // 0..35
    const int tid   = threadIdx.x;
    const int o     = tid & (C3 - 1);
    const int half  = tid >> 7;

    if (chunk < 32) {
        const int c0 = chunk * 8;
        __shared__ float ea_s[N * 6];
        __shared__ float h2_s[N * 8];
        if (tid < N * 6) { int i = tid / 6, v = tid % 6; ea_s[tid] = ea[(i * N + j) * 6 + v]; }
        for (int t = tid; t < N * 8; t += 256) {
            int i = t >> 3, cc = t & 7;
            int c = c0 + cc;
            h2_s[t] = fmaxf(agg2[i * C2 + c] + bias2[c], 0.f);
        }
        __syncthreads();

        float wv[8][6], bb[8], acc[8];
#pragma unroll
        for (int cc = 0; cc < 8; ++cc) {
            int col = (c0 + cc) * C3 + o;
#pragma unroll
            for (int v = 0; v < 6; ++v) wv[cc][v] = w3[v * (C2 * C3) + col];
            bb[cc] = b3[col];
            acc[cc] = 0.f;
        }
        // split the i-loop across the two o-halves
        const int ibeg = half ? 18 : 0;
        const int iend = half ? N  : 18;
        for (int i = ibeg; i < iend; ++i) {
            const float2 e01 = *(const float2*)&ea_s[i * 6];
            const float2 e23 = *(const float2*)&ea_s[i * 6 + 2];
            const float2 e45 = *(const float2*)&ea_s[i * 6 + 4];
            const float4 ha  = *(const float4*)&h2_s[i * 8];
            const float4 hb  = *(const float4*)&h2_s[i * 8 + 4];
            const float hv[8] = {ha.x, ha.y, ha.z, ha.w, hb.x, hb.y, hb.z, hb.w};
#pragma unroll
            for (int cc = 0; cc < 8; ++cc) {
                float p = fmaf(e01.x, wv[cc][0], bb[cc]);
                p = fmaf(e01.y, wv[cc][1], p);
                p = fmaf(e23.x, wv[cc][2], p);
                p = fmaf(e23.y, wv[cc][3], p);
                p = fmaf(e45.x, wv[cc][4], p);
                p = fmaf(e45.y, wv[cc][5], p);
                p = fmaxf(p, 0.f);
                acc[cc] = fmaf(hv[cc], p, acc[cc]);
            }
        }
        float s = 0.f;
#pragma unroll
        for (int cc = 0; cc < 8; ++cc) s += acc[cc];
        atomicAdd(&agg3[j * C3 + o], s * (1.f / N));
    } else {
        // root contribution: 64 c's per chunk, 32 per half
        const int c0 = (chunk - 32) * 64 + half * 32;
        float s = 0.f;
#pragma unroll 8
        for (int c = c0; c < c0 + 32; ++c) {
            float hv = fmaxf(agg2[j * C2 + c] + bias2[c], 0.f);
            s = fmaf(hv, root3[c * C3 + o], s);
        }
        atomicAdd(&agg3[j * C3 + o], s);
    }
}

// ---------------- CBT: pairwise L1 distance, h3 = relu(agg3+bias3) on the fly ----------------
__global__ __launch_bounds__(256) void k_cbt(
    const float* __restrict__ agg3, const float* __restrict__ bias3,
    float* __restrict__ out)
{
    int t = blockIdx.x * 256 + threadIdx.x;
    if (t >= E) return;
    int i = t / N, j = t % N;
    float acc = 0.f;
#pragma unroll
    for (int f = 0; f < C3 / 4; ++f) {
        float4 a  = *(const float4*)&agg3[i * C3 + f * 4];
        float4 b  = *(const float4*)&agg3[j * C3 + f * 4];
        float4 bi = *(const float4*)&bias3[f * 4];
        float ax = fmaxf(a.x + bi.x, 0.f), bx = fmaxf(b.x + bi.x, 0.f);
        float ay = fmaxf(a.y + bi.y, 0.f), by = fmaxf(b.y + bi.y, 0.f);
        float az = fmaxf(a.z + bi.z, 0.f), bz = fmaxf(b.z + bi.z, 0.f);
        float aw = fmaxf(a.w + bi.w, 0.f), bw = fmaxf(b.w + bi.w, 0.f);
        acc += fabsf(bx - ax) + fabsf(by - ay) + fabsf(bz - az) + fabsf(bw - aw);
    }
    out[t] = acc;
}

extern "C" void kernel_launch(void* const* d_in, const int* in_sizes, int n_in,
                              void* d_out, int out_size, void* d_ws, size_t ws_size,
                              hipStream_t stream)
{
    const float* x     = (const float*)d_in[0];
    const float* ea    = (const float*)d_in[1];
    // d_in[2] = edge_index, unused: topology is static (src=e/35, dst=e%35)
    const float* nn1w  = (const float*)d_in[3];
    const float* nn1b  = (const float*)d_in[4];
    const float* nn2w  = (const float*)d_in[5];
    const float* nn2b  = (const float*)d_in[6];
    const float* nn3w  = (const float*)d_in[7];
    const float* nn3b  = (const float*)d_in[8];
    const float* root1 = (const float*)d_in[9];
    const float* bias1 = (const float*)d_in[10];
    const float* root2 = (const float*)d_in[11];
    const float* bias2 = (const float*)d_in[12];
    const float* root3 = (const float*)d_in[13];
    const float* bias3 = (const float*)d_in[14];

    float* ws   = (float*)d_ws;
    float* h1   = ws;
    float* agg2 = ws + 8960;
    float* agg3 = ws + 8960 + 8960;

    // zero the atomic accumulators every call (agg2+agg3 contiguous)
    hipMemsetAsync(agg2, 0, (8960 + 4480) * sizeof(float), stream);

    k_layer1<<<N, C1, 0, stream>>>(x, ea, nn1w, nn1b, root1, bias1, h1);
    k_l2<<<N * 40, 256, 0, stream>>>(ea, nn2w, nn2b, h1, root2, agg2);
    k_l3<<<N * 36, 256, 0, stream>>>(ea, nn3w, nn3b, agg2, bias2, root3, agg3);
    k_cbt<<<(E + 255) / 256, 256, 0, stream>>>(agg3, bias3, (float*)d_out);
}

// Round 3
// 43.738 us; speedup vs baseline: 2.3267x; 1.1136x over previous
//
#include <hip/hip_runtime.h>

#define N  35
#define E  (N*N)
#define C1 256
#define C2 256
#define C3 128

// Workspace layout (floats):
//   h1   @ 0     : 35*256 = 8960
//   agg2 @ 8960  : 35*256 = 8960   (accumulators, zeroed by k_layer1 each call;
//   agg3 @ 17920 : 35*128 = 4480    hold PRE-activation: msg/35 + h@root. bias+relu at read.)

// ---------------- Layer 1: cin=1, cout=256 (also zeroes agg2/agg3) ----------------
__global__ __launch_bounds__(C1) void k_layer1(
    const float* __restrict__ x, const float* __restrict__ ea,
    const float* __restrict__ nn1w, const float* __restrict__ nn1b,
    const float* __restrict__ root1, const float* __restrict__ bias1,
    float* __restrict__ h1, float* __restrict__ aggz)
{
    // zero the agg2+agg3 accumulators (13440 floats); stream order makes this
    // visible to k_l2/k_l3 which run strictly after this kernel.
    for (int t = blockIdx.x * blockDim.x + threadIdx.x; t < 8960 + 4480;
         t += gridDim.x * blockDim.x)
        aggz[t] = 0.f;

    int j = blockIdx.x;
    int o = threadIdx.x;
    float w[6];
#pragma unroll
    for (int v = 0; v < 6; ++v) w[v] = nn1w[v * C1 + o];
    float b = nn1b[o];
    float acc = 0.f;
    for (int i = 0; i < N; ++i) {
        int e = i * N + j;                 // src=i, dst=j
        float p = b;
#pragma unroll
        for (int v = 0; v < 6; ++v) p = fmaf(ea[e * 6 + v], w[v], p);
        p = fmaxf(p, 0.f);
        acc = fmaf(x[i], p, acc);
    }
    float s = acc * (1.f / N) + x[j] * root1[o] + bias1[o];
    h1[j * C1 + o] = fmaxf(s, 0.f);
}

// ---------------- Layer 2: msg chunks (32 x 8c) + root chunks (8 x 32c) ----------------
__global__ __launch_bounds__(256) void k_l2(
    const float* __restrict__ ea,
    const float* __restrict__ w2, const float* __restrict__ b2,
    const float* __restrict__ h1, const float* __restrict__ root2,
    float* __restrict__ agg2)
{
    const int j     = blockIdx.x % N;
    const int chunk = blockIdx.x / N;   // 0..39
    const int o     = threadIdx.x;

    if (chunk < 32) {
        const int c0 = chunk * 8;
        __shared__ float ea_s[N * 6];
        __shared__ float h1_s[N * 8];
        if (o < N * 6) { int i = o / 6, v = o % 6; ea_s[o] = ea[(i * N + j) * 6 + v]; }
        for (int t = o; t < N * 8; t += 256) {
            int i = t >> 3, cc = t & 7;
            h1_s[t] = h1[i * C1 + c0 + cc];
        }
        __syncthreads();

        float wv[8][6], bb[8], acc[8];
#pragma unroll
        for (int cc = 0; cc < 8; ++cc) {
            int col = (c0 + cc) * C2 + o;
#pragma unroll
            for (int v = 0; v < 6; ++v) wv[cc][v] = w2[v * (C1 * C2) + col];
            bb[cc] = b2[col];
            acc[cc] = 0.f;
        }
#pragma unroll 5
        for (int i = 0; i < N; ++i) {
            const float2 e01 = *(const float2*)&ea_s[i * 6];
            const float2 e23 = *(const float2*)&ea_s[i * 6 + 2];
            const float2 e45 = *(const float2*)&ea_s[i * 6 + 4];
            const float4 ha  = *(const float4*)&h1_s[i * 8];
            const float4 hb  = *(const float4*)&h1_s[i * 8 + 4];
            const float hv[8] = {ha.x, ha.y, ha.z, ha.w, hb.x, hb.y, hb.z, hb.w};
#pragma unroll
            for (int cc = 0; cc < 8; ++cc) {
                float p = fmaf(e01.x, wv[cc][0], bb[cc]);
                p = fmaf(e01.y, wv[cc][1], p);
                p = fmaf(e23.x, wv[cc][2], p);
                p = fmaf(e23.y, wv[cc][3], p);
                p = fmaf(e45.x, wv[cc][4], p);
                p = fmaf(e45.y, wv[cc][5], p);
                p = fmaxf(p, 0.f);
                acc[cc] = fmaf(hv[cc], p, acc[cc]);
            }
        }
        float s = 0.f;
#pragma unroll
        for (int cc = 0; cc < 8; ++cc) s += acc[cc];
        atomicAdd(&agg2[j * C2 + o], s * (1.f / N));
    } else {
        // root contribution: 32 c's per chunk
        const int c0 = (chunk - 32) * 32;
        float s = 0.f;
#pragma unroll 8
        for (int c = c0; c < c0 + 32; ++c)
            s = fmaf(h1[j * C1 + c], root2[c * C2 + o], s);
        atomicAdd(&agg2[j * C2 + o], s);
    }
}

// ---------------- Layer 3: msg chunks (32 x 8c) + root chunks (4 x 64c) ----------------
// h2(i,c) = relu(agg2[i,c] + bias2[c]) computed on the fly.
__global__ __launch_bounds__(256) void k_l3(
    const float* __restrict__ ea,
    const float* __restrict__ w3, const float* __restrict__ b3,
    const float* __restrict__ agg2, const float* __restrict__ bias2,
    const float* __restrict__ root3,
    float* __restrict__ agg3)
{
    const int j     = blockIdx.x % N;
    const int chunk = blockIdx.x / N;   // 0..35
    const int tid   = threadIdx.x;
    const int o     = tid & (C3 - 1);
    const int half  = tid >> 7;

    if (chunk < 32) {
        const int c0 = chunk * 8;
        __shared__ float ea_s[N * 6];
        __shared__ float h2_s[N * 8];
        if (tid < N * 6) { int i = tid / 6, v = tid % 6; ea_s[tid] = ea[(i * N + j) * 6 + v]; }
        for (int t = tid; t < N * 8; t += 256) {
            int i = t >> 3, cc = t & 7;
            int c = c0 + cc;
            h2_s[t] = fmaxf(agg2[i * C2 + c] + bias2[c], 0.f);
        }
        __syncthreads();

        float wv[8][6], bb[8], acc[8];
#pragma unroll
        for (int cc = 0; cc < 8; ++cc) {
            int col = (c0 + cc) * C3 + o;
#pragma unroll
            for (int v = 0; v < 6; ++v) wv[cc][v] = w3[v * (C2 * C3) + col];
            bb[cc] = b3[col];
            acc[cc] = 0.f;
        }
        // split the i-loop across the two o-halves
        const int ibeg = half ? 18 : 0;
        const int iend = half ? N  : 18;
        for (int i = ibeg; i < iend; ++i) {
            const float2 e01 = *(const float2*)&ea_s[i * 6];
            const float2 e23 = *(const float2*)&ea_s[i * 6 + 2];
            const float2 e45 = *(const float2*)&ea_s[i * 6 + 4];
            const float4 ha  = *(const float4*)&h2_s[i * 8];
            const float4 hb  = *(const float4*)&h2_s[i * 8 + 4];
            const float hv[8] = {ha.x, ha.y, ha.z, ha.w, hb.x, hb.y, hb.z, hb.w};
#pragma unroll
            for (int cc = 0; cc < 8; ++cc) {
                float p = fmaf(e01.x, wv[cc][0], bb[cc]);
                p = fmaf(e01.y, wv[cc][1], p);
                p = fmaf(e23.x, wv[cc][2], p);
                p = fmaf(e23.y, wv[cc][3], p);
                p = fmaf(e45.x, wv[cc][4], p);
                p = fmaf(e45.y, wv[cc][5], p);
                p = fmaxf(p, 0.f);
                acc[cc] = fmaf(hv[cc], p, acc[cc]);
            }
        }
        float s = 0.f;
#pragma unroll
        for (int cc = 0; cc < 8; ++cc) s += acc[cc];
        atomicAdd(&agg3[j * C3 + o], s * (1.f / N));
    } else {
        // root contribution: 64 c's per chunk, 32 per half
        const int c0 = (chunk - 32) * 64 + half * 32;
        float s = 0.f;
#pragma unroll 8
        for (int c = c0; c < c0 + 32; ++c) {
            float hv = fmaxf(agg2[j * C2 + c] + bias2[c], 0.f);
            s = fmaf(hv, root3[c * C3 + o], s);
        }
        atomicAdd(&agg3[j * C3 + o], s);
    }
}

// ---------------- CBT: pairwise L1 distance, h3 = relu(agg3+bias3) on the fly ----------------
__global__ __launch_bounds__(256) void k_cbt(
    const float* __restrict__ agg3, const float* __restrict__ bias3,
    float* __restrict__ out)
{
    int t = blockIdx.x * 256 + threadIdx.x;
    if (t >= E) return;
    int i = t / N, j = t % N;
    float acc = 0.f;
#pragma unroll
    for (int f = 0; f < C3 / 4; ++f) {
        float4 a  = *(const float4*)&agg3[i * C3 + f * 4];
        float4 b  = *(const float4*)&agg3[j * C3 + f * 4];
        float4 bi = *(const float4*)&bias3[f * 4];
        float ax = fmaxf(a.x + bi.x, 0.f), bx = fmaxf(b.x + bi.x, 0.f);
        float ay = fmaxf(a.y + bi.y, 0.f), by = fmaxf(b.y + bi.y, 0.f);
        float az = fmaxf(a.z + bi.z, 0.f), bz = fmaxf(b.z + bi.z, 0.f);
        float aw = fmaxf(a.w + bi.w, 0.f), bw = fmaxf(b.w + bi.w, 0.f);
        acc += fabsf(bx - ax) + fabsf(by - ay) + fabsf(bz - az) + fabsf(bw - aw);
    }
    out[t] = acc;
}

extern "C" void kernel_launch(void* const* d_in, const int* in_sizes, int n_in,
                              void* d_out, int out_size, void* d_ws, size_t ws_size,
                              hipStream_t stream)
{
    const float* x     = (const float*)d_in[0];
    const float* ea    = (const float*)d_in[1];
    // d_in[2] = edge_index, unused: topology is static (src=e/35, dst=e%35)
    const float* nn1w  = (const float*)d_in[3];
    const float* nn1b  = (const float*)d_in[4];
    const float* nn2w  = (const float*)d_in[5];
    const float* nn2b  = (const float*)d_in[6];
    const float* nn3w  = (const float*)d_in[7];
    const float* nn3b  = (const float*)d_in[8];
    const float* root1 = (const float*)d_in[9];
    const float* bias1 = (const float*)d_in[10];
    const float* root2 = (const float*)d_in[11];
    const float* bias2 = (const float*)d_in[12];
    const float* root3 = (const float*)d_in[13];
    const float* bias3 = (const float*)d_in[14];

    float* ws   = (float*)d_ws;
    float* h1   = ws;
    float* agg2 = ws + 8960;
    float* agg3 = ws + 8960 + 8960;

    // k_layer1 zeroes agg2+agg3 (contiguous) at entry — no memset node needed.
    k_layer1<<<N, C1, 0, stream>>>(x, ea, nn1w, nn1b, root1, bias1, h1, agg2);
    k_l2<<<N * 40, 256, 0, stream>>>(ea, nn2w, nn2b, h1, root2, agg2);
    k_l3<<<N * 36, 256, 0, stream>>>(ea, nn3w, nn3b, agg2, bias2, root3, agg3);
    k_cbt<<<(E + 255) / 256, 256, 0, stream>>>(agg3, bias3, (float*)d_out);
}